// Round 5
// baseline (116.595 us; speedup 1.0000x reference)
//
#include <hip/hip_runtime.h>
#include <math.h>

// PRNN J2 plane-strain elastoplasticity scan.
// B=16384, T=128, F=3, MATPTS=16 (P=262144), O=3.
// R15: SCHEDULING-FENCE PROBE. R10/R12/R13/R14 all pin at ~55-60us across
// {2 waves x 1 chain, 1 wave x 2 chains, 4- vs 8-step windows}: every config
// kept the volatile-asm DPP butterfly -- a scheduler fence every 8 steps with
// DPP RAW hazards, putting the Z-reduce on the VALU port in series with
// physics. R15 replaces it with a WAVE-PRIVATE LDS transpose reduce:
//  * producers ds_write 3 cumulative-Z scalars/step into a per-wave 6KiB
//    region (2-way bank aliasing only = free);
//  * at body end lanes 0..23 read one (comp c, batch G) row as 2x float4,
//    sum 8 floats, combine with M.x (moved by one ds_bpermute shfl per
//    step), and store out[G][t][c].
//  * NO barriers (within-wave DS is in-order; regions are wave-private),
//    NO asm fences, NO DPP in the loop -> scheduler free across whole body;
//    reduction rides the idle LDS pipe.
// Physics identical to R13 (deviatoric W1 rows, sqrt2-folded shear,
// g=fma(-Y,rq,1) yield, trace-free-p identity). Layout: 8 lanes/batch,
// 2 pts/lane (v2 -> v_pk_fma_f32), 32 batches/block, 512 blocks, 2 w/SIMD.

#define BLOCK 256
#define BPB 32              // batch elements per block (8 lanes each)
#define TSTEPS 128
#define ROWF (TSTEPS * 3)   // 384 floats per batch row

typedef float v2 __attribute__((ext_vector_type(2)));

static __device__ __forceinline__ v2 vfma(v2 a, v2 b, v2 c) {
    return __builtin_elementwise_fma(a, b, c);
}
static __device__ __forceinline__ v2 vmax(v2 a, v2 b) {
    return __builtin_elementwise_max(a, b);
}

// schedulable DPP add stage (init-only use)
#define DPP_ADDST(v, ctrl)                                                   \
    v += __int_as_float(__builtin_amdgcn_update_dpp(                         \
        0, __float_as_int(v), (ctrl), 0xf, 0xf, true))
// 8-lane butterfly: quad_perm xor1 (0xB1), xor2 (0x4E), row_half_mirror (0x141)
#define RED8(v)                                                              \
    do { DPP_ADDST(v, 0xB1); DPP_ADDST(v, 0x4E); DPP_ADDST(v, 0x141); } while (0)

__global__ __launch_bounds__(BLOCK, 2)
void prnn_j2_kernel(const float* __restrict__ x,
                    const float* __restrict__ W1,
                    const float* __restrict__ W2,
                    float* __restrict__ out)
{
    constexpr float MU    = (float)(3130.0 / (2.0 * (1.0 + 0.37)));
    constexpr float LAM   = (float)(3130.0 * 0.37 / ((1.0 + 0.37) * (1.0 - 2.0 * 0.37)));
    constexpr float SIG_Y = 64.8f;
    constexpr float H_ISO = 300.0f;
    const float TWO_MU  = 2.0f * MU;
    const float INV_DEN = 1.0f / (3.0f * MU + H_ISO);
    const float K3P     = (3.0f * MU) * INV_DEN;      // k = K3P * gm
    const float HP      = H_ISO * INV_DEN;            // Y += HP * fY
    const float CSC     = 1.0f / (MU * 2.4494897427831781f);  // 1/(MU*sqrt6)
    const float Y0      = SIG_Y * CSC;
    const float SQRT2   = 1.41421356237309515f;
    const float RSQRT2  = 0.70710678118654752f;

    // [wave][s=8][c=3][G=8][l=8] floats; 1536 words/wave, wave-private.
    __shared__ float LDSR[4 * 1536];

    const int tid = threadIdx.x;
    const int g   = tid >> 3;       // local batch 0..31
    const int l   = tid & 7;        // lane in 8-group; points (l, l+8)
    const int gb  = blockIdx.x * BPB + g;   // global batch

    const int wv  = tid >> 6;       // wave 0..3
    const int Gw  = g & 7;          // batch-in-wave 0..7
    // producer write base (word): + s*192 + c*64 folds to imm offsets
    const int wword = wv * 1536 + Gw * 8 + l;
    // reader mapping: wave-lane j<24 -> (G=j/3, c=j%3)
    const int j   = tid & 63;
    const int jc  = (j < 24) ? j : 0;
    const int Gr  = (jc * 11) >> 5;         // jc/3 for jc<24
    const int cr  = jc - 3 * Gr;
    const int srcl  = Gr * 8 + cr;          // shfl source lane (l=cr<3: Mrow valid)
    const int rword = wv * 1536 + cr * 64 + Gr * 8;
    float* orow = out + (blockIdx.x * BPB + wv * 8 + Gr) * ROWF + cr;

    const float* xb = x + gb * ROWF;

    // ---- packed per-thread weights: .x = point l, .y = point l+8 ----
    const int pa = l, pb = l + 8;
    v2 w1r0[3], w1r1[3], w1h2[3];      // raw row0, row1, half row2
    #pragma unroll
    for (int f = 0; f < 3; ++f) {
        w1r0[f].x = W1[(3 * pa + 0) * 3 + f];
        w1r0[f].y = W1[(3 * pb + 0) * 3 + f];
        w1r1[f].x = W1[(3 * pa + 1) * 3 + f];
        w1r1[f].y = W1[(3 * pb + 1) * 3 + f];
        w1h2[f].x = 0.5f * W1[(3 * pa + 2) * 3 + f];
        w1h2[f].y = 0.5f * W1[(3 * pb + 2) * 3 + f];
    }
    v2 w2p[3][3];
    #pragma unroll
    for (int o = 0; o < 3; ++o)
        #pragma unroll
        for (int c = 0; c < 3; ++c) {
            float wa = W2[o * 48 + 3 * pa + c];
            float wb = W2[o * 48 + 3 * pb + c];
            w2p[o][c].x = fmaxf(wa, 0.0f) + log1pf(expf(-fabsf(wa)));
            w2p[o][c].y = fmaxf(wb, 0.0f) + log1pf(expf(-fabsf(wb)));
        }

    // ---- constant elastic map M[o][f] = sum_p w2s_p . C . W1_p ----
    float Mrow[3];   // this lane's output-component row (l<3), else junk
    {
        float Ms[3][3];
        #pragma unroll
        for (int f = 0; f < 3; ++f) {
            v2 ax = (LAM + TWO_MU) * w1r0[f] + LAM * w1r1[f];
            v2 ay = LAM * w1r0[f] + (LAM + TWO_MU) * w1r1[f];
            v2 as = TWO_MU * w1h2[f];
            #pragma unroll
            for (int o = 0; o < 3; ++o) {
                v2 mp = vfma(w2p[o][0], ax, vfma(w2p[o][1], ay, w2p[o][2] * as));
                float ms = mp.x + mp.y;
                RED8(ms);               // sum over the 8 lanes (all 16 points)
                Ms[o][f] = ms;
            }
        }
        #pragma unroll
        for (int f = 0; f < 3; ++f) {
            float v = (l == 0) ? Ms[0][f] : ((l == 1) ? Ms[1][f] : Ms[2][f]);
            Mrow[f] = v;
        }
    }

    // ---- loop-form weights: deviatoric rows + sqrt2-folded shear ----
    v2 wdx[3], wdy[3], wsh[3];
    #pragma unroll
    for (int f = 0; f < 3; ++f) {
        wdx[f] = (2.0f * w1r0[f] - w1r1[f]) * (1.0f / 3.0f);  // ex0 = wdx.x
        wdy[f] = (2.0f * w1r1[f] - w1r0[f]) * (1.0f / 3.0f);  // ey0 = wdy.x
        wsh[f] = SQRT2 * w1h2[f];                              // exy2-elastic
    }
    #pragma unroll
    for (int o = 0; o < 3; ++o) w2p[o][2] *= RSQRT2;  // dps = sqrt2*dp3

    v2 p0 = {0.f,0.f}, p1 = {0.f,0.f}, ps = {0.f,0.f};
    v2 Y  = {Y0, Y0};
    v2 z0 = {0.f,0.f}, z1 = {0.f,0.f}, z2 = {0.f,0.f};

    const float4* xv = (const float4*)xb;   // group-uniform broadcast loads

// Carry chain: p0 -> exd -> ua -> u -> max -> rq -> g -> gm -> k -> kdx -> p0.
// zs/mx/ds_write hang OFF the chain; no cross-lane ops in the step.
#define J2_PHYS(x0_, x1_, x2_, S)                                            \
  {                                                                          \
    const float x0s = (x0_), x1s = (x1_), x2s = (x2_);                       \
    const v2 x0 = {x0s, x0s}, x1 = {x1s, x1s}, x2 = {x2s, x2s};              \
    const v2 ex0 = vfma(wdx[0], x0, vfma(wdx[1], x1, wdx[2] * x2));          \
    const v2 ey0 = vfma(wdy[0], x0, vfma(wdy[1], x1, wdy[2] * x2));          \
    const v2 wsy = vfma(wsh[0], x0, vfma(wsh[1], x1, wsh[2] * x2));          \
    const v2 exd = ex0 - p0;                                                 \
    const v2 eyd = ey0 - p1;                                                 \
    const v2 exy = wsy - ps;                                                 \
    const v2 szd = exd + eyd;           /* = -ezd, exact */                  \
    const v2 ua = vfma(eyd, eyd, exd * exd);                                 \
    const v2 ub = vfma(exy, exy, szd * szd);                                 \
    v2 u = ua + ub;                                                          \
    u = vmax(u, (v2){1e-30f, 1e-30f});                                       \
    v2 rq;                                                                   \
    rq.x = __builtin_amdgcn_rsqf(u.x);                                       \
    rq.y = __builtin_amdgcn_rsqf(u.y);                                       \
    const v2 gm = vmax(vfma(-Y, rq, (v2){1.0f, 1.0f}), (v2){0.0f, 0.0f});    \
    const v2 su = u * rq;               /* sqrt(u), Y side-chain only */     \
    const v2 k  = K3P * gm;                                                  \
    Y = vfma((v2){HP, HP}, gm * su, Y); /* fY = gm*su = max(su-Y,0) */       \
    const v2 kdx = k * exd;                                                  \
    const v2 kdy = k * eyd;                                                  \
    const v2 kdp = k * exy;                                                  \
    p0 += kdx;                                                               \
    p1 += kdy;                                                               \
    ps += kdp;                                                               \
    z0 = vfma(w2p[0][0], kdx, vfma(w2p[0][1], kdy, vfma(w2p[0][2], kdp, z0)));\
    z1 = vfma(w2p[1][0], kdx, vfma(w2p[1][1], kdy, vfma(w2p[1][2], kdp, z1)));\
    z2 = vfma(w2p[2][0], kdx, vfma(w2p[2][1], kdy, vfma(w2p[2][2], kdp, z2)));\
    LDSR[wword + (S) * 192 +   0] = z0.x + z0.y;                             \
    LDSR[wword + (S) * 192 +  64] = z1.x + z1.y;                             \
    LDSR[wword + (S) * 192 + 128] = z2.x + z2.y;                             \
    mx[S] = fmaf(Mrow[0], x0s, fmaf(Mrow[1], x1s, Mrow[2] * x2s));           \
  }

    float4 A0 = xv[0], A1 = xv[1], A2 = xv[2];
    float4 A3 = xv[3], A4 = xv[4], A5 = xv[5];

    for (int tb = 0; tb < TSTEPS / 8; ++tb) {
        // distance-1 prefetch; last iteration re-loads the same block (no OOB)
        const int nb = (tb < TSTEPS / 8 - 1) ? (6 * tb + 6) : (6 * tb);
        float4 An0 = xv[nb + 0];
        float4 An1 = xv[nb + 1];
        float4 An2 = xv[nb + 2];
        float4 An3 = xv[nb + 3];
        float4 An4 = xv[nb + 4];
        float4 An5 = xv[nb + 5];

        float mx[8];
        J2_PHYS(A0.x, A0.y, A0.z, 0);
        J2_PHYS(A0.w, A1.x, A1.y, 1);
        J2_PHYS(A1.z, A1.w, A2.x, 2);
        J2_PHYS(A2.y, A2.z, A2.w, 3);
        J2_PHYS(A3.x, A3.y, A3.z, 4);
        J2_PHYS(A3.w, A4.x, A4.y, 5);
        J2_PHYS(A4.z, A4.w, A5.x, 6);
        J2_PHYS(A5.y, A5.z, A5.w, 7);

        // move M.x across lanes (full exec: source lanes must be active)
        float mxs[8];
        #pragma unroll
        for (int s = 0; s < 8; ++s)
            mxs[s] = __shfl(mx[s], srcl, 64);

        // wave-private transpose reduce: lane j<24 owns (G=j/3, c=j%3)
        if (j < 24) {
            #pragma unroll
            for (int s = 0; s < 8; ++s) {
                const float4 lo = *(const float4*)&LDSR[rword + s * 192];
                const float4 hi = *(const float4*)&LDSR[rword + s * 192 + 4];
                float4 q;
                q.x = lo.x + hi.x; q.y = lo.y + hi.y;
                q.z = lo.z + hi.z; q.w = lo.w + hi.w;
                const float h = (q.x + q.y) + (q.z + q.w);
                orow[tb * 24 + s * 3] = fmaf(-TWO_MU, h, mxs[s]);
            }
        }

        A0 = An0; A1 = An1; A2 = An2;
        A3 = An3; A4 = An4; A5 = An5;
    }
#undef J2_PHYS
}

extern "C" void kernel_launch(void* const* d_in, const int* in_sizes, int n_in,
                              void* d_out, int out_size, void* d_ws, size_t ws_size,
                              hipStream_t stream) {
    const float* x  = (const float*)d_in[0];
    const float* W1 = (const float*)d_in[1];
    const float* W2 = (const float*)d_in[2];
    float* out = (float*)d_out;

    const int B = 16384;
    dim3 grid(B / BPB);   // 512 blocks, 2 waves/SIMD
    dim3 block(BLOCK);
    prnn_j2_kernel<<<grid, block, 0, stream>>>(x, W1, W2, out);
}

// Round 6
// 113.984 us; speedup vs baseline: 1.0229x; 1.0229x over previous
//
#include <hip/hip_runtime.h>
#include <math.h>

// PRNN J2 plane-strain elastoplasticity scan.
// B=16384, T=128, F=3, MATPTS=16 (P=262144), O=3.
// R16: R13 base (best: 55.4us) + STORE-DRAIN + COPY elimination.
// Ledger: R12 chain-shorten null; R14 ILP-2@1wave null; R15 LDS-reduce
// regressed (bank conflicts + lgkmcnt, fence theory refuted). Remaining
// synchronized-stall candidates: (a) vmcnt store-drain waits -- r[] regs
// feeding the 8 scattered dword stores are rewritten ~50 insts later by the
// next body's step 0, so both waves wait on store retirement in phase every
// body; (b) 24 v_mov/body for the A=An buffer rotation (no modulo renaming
// in a rolled loop). Fix both:
//  * outer unroll x2, P/Q ping-pong float4 sets: loads write directly into
//    the off-duty set (copies gone); load-to-use distance = 1 half-body.
//  * per-half r[]/mx[] buffers: store->reg-reuse distance ~50 -> ~540 insts,
//    vmcnt waits drop out of the steady state.
//  * u-clamp folded into innermost fma (exd^2 + 1e-30): -2 scalar max/step.
// Physics identical to R13 (deviatoric W1 rows, sqrt2-folded shear,
// g=fma(-Y,rq,1) yield, trace-free-p identity). Layout: 8 lanes/batch,
// 2 pts/lane (v2 -> v_pk_fma_f32), 32 batches/block, 512 blocks, 2 w/SIMD.

#define BLOCK 256
#define BPB 32              // batch elements per block (8 lanes each)
#define TSTEPS 128
#define ROWF (TSTEPS * 3)   // 384 floats per batch row

typedef float v2 __attribute__((ext_vector_type(2)));

static __device__ __forceinline__ v2 vfma(v2 a, v2 b, v2 c) {
    return __builtin_elementwise_fma(a, b, c);
}
static __device__ __forceinline__ v2 vmax(v2 a, v2 b) {
    return __builtin_elementwise_max(a, b);
}

// schedulable DPP add stage (init-only use)
#define DPP_ADDST(v, ctrl)                                                   \
    v += __int_as_float(__builtin_amdgcn_update_dpp(                         \
        0, __float_as_int(v), (ctrl), 0xf, 0xf, true))
// 8-lane butterfly: quad_perm xor1 (0xB1), xor2 (0x4E), row_half_mirror (0x141)
#define RED8(v)                                                              \
    do { DPP_ADDST(v, 0xB1); DPP_ADDST(v, 0x4E); DPP_ADDST(v, 0x141); } while (0)

// batched asm butterfly for the 24 in-loop partials
#define DPP_ST(r, ctrl) "v_add_f32_dpp %" #r ", %" #r ", %" #r " " ctrl \
                        " row_mask:0xf bank_mask:0xf\n\t"
#define DPP_STAGE24(ctrl) \
    DPP_ST(0, ctrl)  DPP_ST(1, ctrl)  DPP_ST(2, ctrl)  DPP_ST(3, ctrl)  \
    DPP_ST(4, ctrl)  DPP_ST(5, ctrl)  DPP_ST(6, ctrl)  DPP_ST(7, ctrl)  \
    DPP_ST(8, ctrl)  DPP_ST(9, ctrl)  DPP_ST(10, ctrl) DPP_ST(11, ctrl) \
    DPP_ST(12, ctrl) DPP_ST(13, ctrl) DPP_ST(14, ctrl) DPP_ST(15, ctrl) \
    DPP_ST(16, ctrl) DPP_ST(17, ctrl) DPP_ST(18, ctrl) DPP_ST(19, ctrl) \
    DPP_ST(20, ctrl) DPP_ST(21, ctrl) DPP_ST(22, ctrl) DPP_ST(23, ctrl)
#define DPP_BFLY24(a0,a1,a2,a3,a4,a5,a6,a7,a8,a9,a10,a11,                    \
                   a12,a13,a14,a15,a16,a17,a18,a19,a20,a21,a22,a23)          \
  asm volatile(                                                              \
    "s_nop 1\n\t"                                                            \
    DPP_STAGE24("quad_perm:[1,0,3,2]")                                       \
    DPP_STAGE24("quad_perm:[2,3,0,1]")                                       \
    DPP_STAGE24("row_half_mirror")                                           \
    : "+v"(a0), "+v"(a1), "+v"(a2), "+v"(a3), "+v"(a4), "+v"(a5),            \
      "+v"(a6), "+v"(a7), "+v"(a8), "+v"(a9), "+v"(a10), "+v"(a11),          \
      "+v"(a12), "+v"(a13), "+v"(a14), "+v"(a15), "+v"(a16), "+v"(a17),      \
      "+v"(a18), "+v"(a19), "+v"(a20), "+v"(a21), "+v"(a22), "+v"(a23))

__global__ __launch_bounds__(BLOCK, 2)
void prnn_j2_kernel(const float* __restrict__ x,
                    const float* __restrict__ W1,
                    const float* __restrict__ W2,
                    float* __restrict__ out)
{
    constexpr float MU    = (float)(3130.0 / (2.0 * (1.0 + 0.37)));
    constexpr float LAM   = (float)(3130.0 * 0.37 / ((1.0 + 0.37) * (1.0 - 2.0 * 0.37)));
    constexpr float SIG_Y = 64.8f;
    constexpr float H_ISO = 300.0f;
    const float TWO_MU  = 2.0f * MU;
    const float INV_DEN = 1.0f / (3.0f * MU + H_ISO);
    const float K3P     = (3.0f * MU) * INV_DEN;      // k = K3P * gm
    const float HP      = H_ISO * INV_DEN;            // Y += HP * fY
    const float CSC     = 1.0f / (MU * 2.4494897427831781f);  // 1/(MU*sqrt6)
    const float Y0      = SIG_Y * CSC;
    const float SQRT2   = 1.41421356237309515f;
    const float RSQRT2  = 0.70710678118654752f;

    const int tid = threadIdx.x;
    const int g   = tid >> 3;       // local batch 0..31
    const int l   = tid & 7;        // lane in 8-group; points (l, l+8)
    const int gb  = blockIdx.x * BPB + g;   // global batch

    const float* xb = x + gb * ROWF;
    float* ob = out + gb * ROWF;

    // ---- packed per-thread weights: .x = point l, .y = point l+8 ----
    const int pa = l, pb = l + 8;
    v2 w1r0[3], w1r1[3], w1h2[3];      // raw row0, row1, half row2
    #pragma unroll
    for (int f = 0; f < 3; ++f) {
        w1r0[f].x = W1[(3 * pa + 0) * 3 + f];
        w1r0[f].y = W1[(3 * pb + 0) * 3 + f];
        w1r1[f].x = W1[(3 * pa + 1) * 3 + f];
        w1r1[f].y = W1[(3 * pb + 1) * 3 + f];
        w1h2[f].x = 0.5f * W1[(3 * pa + 2) * 3 + f];
        w1h2[f].y = 0.5f * W1[(3 * pb + 2) * 3 + f];
    }
    v2 w2p[3][3];
    #pragma unroll
    for (int o = 0; o < 3; ++o)
        #pragma unroll
        for (int c = 0; c < 3; ++c) {
            float wa = W2[o * 48 + 3 * pa + c];
            float wb = W2[o * 48 + 3 * pb + c];
            w2p[o][c].x = fmaxf(wa, 0.0f) + log1pf(expf(-fabsf(wa)));
            w2p[o][c].y = fmaxf(wb, 0.0f) + log1pf(expf(-fabsf(wb)));
        }

    // ---- constant elastic map M[o][f] = sum_p w2s_p . C . W1_p ----
    float Mrow[3];   // this lane's output-component row (l<3), else junk
    {
        float Ms[3][3];
        #pragma unroll
        for (int f = 0; f < 3; ++f) {
            v2 ax = (LAM + TWO_MU) * w1r0[f] + LAM * w1r1[f];
            v2 ay = LAM * w1r0[f] + (LAM + TWO_MU) * w1r1[f];
            v2 as = TWO_MU * w1h2[f];
            #pragma unroll
            for (int o = 0; o < 3; ++o) {
                v2 mp = vfma(w2p[o][0], ax, vfma(w2p[o][1], ay, w2p[o][2] * as));
                float ms = mp.x + mp.y;
                RED8(ms);               // sum over the 8 lanes (all 16 points)
                Ms[o][f] = ms;
            }
        }
        #pragma unroll
        for (int f = 0; f < 3; ++f) {
            float v = (l == 0) ? Ms[0][f] : ((l == 1) ? Ms[1][f] : Ms[2][f]);
            Mrow[f] = v;
        }
    }

    // ---- loop-form weights: deviatoric rows + sqrt2-folded shear ----
    v2 wdx[3], wdy[3], wsh[3];
    #pragma unroll
    for (int f = 0; f < 3; ++f) {
        wdx[f] = (2.0f * w1r0[f] - w1r1[f]) * (1.0f / 3.0f);  // ex0 = wdx.x
        wdy[f] = (2.0f * w1r1[f] - w1r0[f]) * (1.0f / 3.0f);  // ey0 = wdy.x
        wsh[f] = SQRT2 * w1h2[f];                              // exy2-elastic
    }
    #pragma unroll
    for (int o = 0; o < 3; ++o) w2p[o][2] *= RSQRT2;  // dps = sqrt2*dp3

    v2 p0 = {0.f,0.f}, p1 = {0.f,0.f}, ps = {0.f,0.f};
    v2 Y  = {Y0, Y0};
    v2 z0 = {0.f,0.f}, z1 = {0.f,0.f}, z2 = {0.f,0.f};

    const float4* xv = (const float4*)xb;   // group-uniform broadcast loads
    const bool wact = (l < 3);
    float* obl = ob + l;

// Carry chain: p0 -> exd -> ua -> u -> rq -> gm -> k -> kdx -> p0.
// eps folded into innermost fma (u >= 1e-30 guaranteed, clamp deleted).
#define J2_PHYS(x0_, x1_, x2_, rr, mxv)                                      \
  {                                                                          \
    const float x0s = (x0_), x1s = (x1_), x2s = (x2_);                       \
    const v2 x0 = {x0s, x0s}, x1 = {x1s, x1s}, x2 = {x2s, x2s};              \
    const v2 ex0 = vfma(wdx[0], x0, vfma(wdx[1], x1, wdx[2] * x2));          \
    const v2 ey0 = vfma(wdy[0], x0, vfma(wdy[1], x1, wdy[2] * x2));          \
    const v2 wsy = vfma(wsh[0], x0, vfma(wsh[1], x1, wsh[2] * x2));          \
    const v2 exd = ex0 - p0;                                                 \
    const v2 eyd = ey0 - p1;                                                 \
    const v2 exy = wsy - ps;                                                 \
    const v2 szd = exd + eyd;           /* = -ezd, exact */                  \
    const v2 ua = vfma(eyd, eyd, vfma(exd, exd, (v2){1e-30f, 1e-30f}));      \
    const v2 ub = vfma(exy, exy, szd * szd);                                 \
    const v2 u = ua + ub;               /* >= 1e-30 by construction */       \
    v2 rq;                                                                   \
    rq.x = __builtin_amdgcn_rsqf(u.x);                                       \
    rq.y = __builtin_amdgcn_rsqf(u.y);                                       \
    const v2 gm = vmax(vfma(-Y, rq, (v2){1.0f, 1.0f}), (v2){0.0f, 0.0f});    \
    const v2 su = u * rq;               /* sqrt(u), Y side-chain only */     \
    const v2 k  = K3P * gm;                                                  \
    Y = vfma((v2){HP, HP}, gm * su, Y); /* fY = gm*su = max(su-Y,0) */       \
    const v2 kdx = k * exd;                                                  \
    const v2 kdy = k * eyd;                                                  \
    const v2 kdp = k * exy;                                                  \
    p0 += kdx;                                                               \
    p1 += kdy;                                                               \
    ps += kdp;                                                               \
    z0 = vfma(w2p[0][0], kdx, vfma(w2p[0][1], kdy, vfma(w2p[0][2], kdp, z0)));\
    z1 = vfma(w2p[1][0], kdx, vfma(w2p[1][1], kdy, vfma(w2p[1][2], kdp, z1)));\
    z2 = vfma(w2p[2][0], kdx, vfma(w2p[2][1], kdy, vfma(w2p[2][2], kdp, z2)));\
    (rr)[0] = z0.x + z0.y;                                                   \
    (rr)[1] = z1.x + z1.y;                                                   \
    (rr)[2] = z2.x + z2.y;                                                   \
    (mxv) = fmaf(Mrow[0], x0s, fmaf(Mrow[1], x1s, Mrow[2] * x2s));           \
  }

// one 4-timestep-pair half: 8 steps from regs S0..S5, reduce, store at block h
#define HALF_BODY(S0, S1, S2, S3, S4, S5, h)                                 \
  {                                                                          \
    float r[24], mx[8];                                                      \
    J2_PHYS(S0.x, S0.y, S0.z, r + 0,  mx[0]);                                \
    J2_PHYS(S0.w, S1.x, S1.y, r + 3,  mx[1]);                                \
    J2_PHYS(S1.z, S1.w, S2.x, r + 6,  mx[2]);                                \
    J2_PHYS(S2.y, S2.z, S2.w, r + 9,  mx[3]);                                \
    J2_PHYS(S3.x, S3.y, S3.z, r + 12, mx[4]);                                \
    J2_PHYS(S3.w, S4.x, S4.y, r + 15, mx[5]);                                \
    J2_PHYS(S4.z, S4.w, S5.x, r + 18, mx[6]);                                \
    J2_PHYS(S5.y, S5.z, S5.w, r + 21, mx[7]);                                \
    DPP_BFLY24(r[0],  r[1],  r[2],  r[3],  r[4],  r[5],                      \
               r[6],  r[7],  r[8],  r[9],  r[10], r[11],                     \
               r[12], r[13], r[14], r[15], r[16], r[17],                     \
               r[18], r[19], r[20], r[21], r[22], r[23]);                    \
    if (wact) {                                                              \
        _Pragma("unroll")                                                    \
        for (int s = 0; s < 8; ++s) {                                        \
            float zz = (l == 0) ? r[3*s] : ((l == 1) ? r[3*s+1] : r[3*s+2]); \
            obl[24 * (h) + 3 * s] = fmaf(-TWO_MU, zz, mx[s]);                \
        }                                                                    \
    }                                                                        \
  }

    // P/Q ping-pong: loads write directly into the off-duty set (no copies).
    float4 P0 = xv[0], P1 = xv[1], P2 = xv[2];
    float4 P3 = xv[3], P4 = xv[4], P5 = xv[5];
    float4 Q0, Q1, Q2, Q3, Q4, Q5;

    for (int it = 0; it < 8; ++it) {
        // ---- half P (time block 2*it); load Q for block 2*it+1 ----
        {
            const int qb = 6 * (2 * it + 1);       // always valid (<=90)
            Q0 = xv[qb + 0]; Q1 = xv[qb + 1]; Q2 = xv[qb + 2];
            Q3 = xv[qb + 3]; Q4 = xv[qb + 4]; Q5 = xv[qb + 5];
            HALF_BODY(P0, P1, P2, P3, P4, P5, 2 * it);
        }
        // ---- half Q (time block 2*it+1); load P for block 2*it+2 ----
        {
            const int pbi = (it < 7) ? 6 * (2 * it + 2) : 0;  // dummy reload last
            P0 = xv[pbi + 0]; P1 = xv[pbi + 1]; P2 = xv[pbi + 2];
            P3 = xv[pbi + 3]; P4 = xv[pbi + 4]; P5 = xv[pbi + 5];
            HALF_BODY(Q0, Q1, Q2, Q3, Q4, Q5, 2 * it + 1);
        }
    }
#undef HALF_BODY
#undef J2_PHYS
}

extern "C" void kernel_launch(void* const* d_in, const int* in_sizes, int n_in,
                              void* d_out, int out_size, void* d_ws, size_t ws_size,
                              hipStream_t stream) {
    const float* x  = (const float*)d_in[0];
    const float* W1 = (const float*)d_in[1];
    const float* W2 = (const float*)d_in[2];
    float* out = (float*)d_out;

    const int B = 16384;
    dim3 grid(B / BPB);   // 512 blocks, 2 waves/SIMD
    dim3 block(BLOCK);
    prnn_j2_kernel<<<grid, block, 0, stream>>>(x, W1, W2, out);
}